// Round 5
// baseline (204.686 us; speedup 1.0000x reference)
//
#include <hip/hip_runtime.h>
#include <cstdint>
#include <cstddef>

#define N_IMG 32
#define C_IN 192
#define HW 56
#define SPAT 3136
#define C_OUT 384
#define HP 58
#define KPOS 9
#define KTOT 1728          // 9*192
#define NT 27              // K-tiles of 64

#define BM 128             // Cout per block
#define BN 256             // spatial-flat per block
#define NT_CO 3
#define NT_S  392          // 100352/256 exact
#define GRID_MAIN (NT_CO*NT_S)   // 1176, %8 == 0

#define BUF_EL 16384       // B-only buffer: 256 rows x 64 k bf16 (32KB)

typedef __attribute__((ext_vector_type(8))) short short8;
typedef __attribute__((ext_vector_type(4))) float f32x4;

__device__ __forceinline__ unsigned short f2bf(float f) {
  union { float f; unsigned u; } v; v.f = f;
  unsigned u = v.u;
  unsigned r = (u + 0x7FFFu + ((u >> 16) & 1u)) >> 16;
  return (unsigned short)r;
}

__device__ __forceinline__ void async_load16(const void* gsrc, void* ldst) {
  __builtin_amdgcn_global_load_lds(
      (const __attribute__((address_space(1))) unsigned int*)gsrc,
      (__attribute__((address_space(3))) unsigned int*)ldst,
      16, 0, 0);
}

__device__ __forceinline__ void vm4() { asm volatile("s_waitcnt vmcnt(4)" ::: "memory"); }
__device__ __forceinline__ void vm0() { asm volatile("s_waitcnt vmcnt(0)" ::: "memory"); }
#define SBAR0() __builtin_amdgcn_sched_barrier(0)

// ---- prep: W (Cout,C,3,3) f32 -> WpF in MFMA-fragment order ----
// block = (co16 = co>>4, k32 = k>>5), element (lane, j):
//   WpF[(co16*54 + k32)*512 + lane*8 + j] = A[co16*16 + (lane&15)][k32*32 + (lane>>4)*8 + j]
// with GEMM k = pos*192 + c.
__global__ void pack_w(const float* __restrict__ W, unsigned short* __restrict__ WpF) {
  int idx = blockIdx.x*256 + threadIdx.x;
  if (idx >= C_OUT*KTOT) return;
  int co = idx / KTOT;
  int k  = idx % KTOT;
  int pos = k / C_IN;
  int c   = k % C_IN;
  float v = W[((size_t)co*C_IN + c)*KPOS + pos];
  int mb = co >> 4, r = co & 15;
  int kb = k >> 5,  cc = k & 31;
  int l  = r + ((cc >> 3) << 4);
  int j  = cc & 7;
  WpF[((size_t)mb*54 + kb)*512 + l*8 + j] = f2bf(v);
}

// ---- prep: zero pad border of Xp[n][58][58][192] ----
__global__ void zero_border(unsigned short* __restrict__ Xp) {
  int idx = blockIdx.x*256 + threadIdx.x;
  if (idx >= N_IMG*228*C_IN) return;
  int c    = idx % C_IN;
  int cell = (idx / C_IN) % 228;
  int n    = idx / (C_IN*228);
  int hh, ww;
  if (cell < 116) { hh = (cell < 58) ? 0 : 57; ww = cell % 58; }
  else { int b2 = cell - 116; ww = (b2 < 56) ? 0 : 57; hh = 1 + (b2 % 56); }
  Xp[(((size_t)n*HP + hh)*HP + ww)*C_IN + c] = 0;
}

// ---- prep: x NCHW f32 -> Xp padded NHWC bf16 (interior) ----
__global__ void pack_x(const float* __restrict__ x, unsigned short* __restrict__ Xp) {
  __shared__ float tile[64*57];
  int b  = blockIdx.x;
  int cb = b % 3;
  int h  = (b/3) % HW;
  int n  = b / (3*HW);
  int tid = threadIdx.x;
  const float* src = x + (size_t)n*C_IN*SPAT + (size_t)cb*64*SPAT + h*HW;
  #pragma unroll
  for (int i = 0; i < 14; ++i) {
    int idx = i*256 + tid;
    int c = idx / HW, w = idx % HW;
    tile[c*57 + w] = src[(size_t)c*SPAT + w];
  }
  __syncthreads();
  unsigned short* dst = Xp + (((size_t)n*HP + h + 1)*HP + 1)*C_IN + cb*64;
  #pragma unroll
  for (int i = 0; i < 14; ++i) {
    int idx = i*256 + tid;
    int w = idx / 64, c = idx % 64;
    dst[(size_t)w*C_IN + c] = f2bf(tile[c*57 + w]);
  }
}

// ---- main: implicit-GEMM conv, 128x256, 8 waves; A direct from global (frag-packed),
//      B through ring-3 LDS, one phase per K=64, counted vmcnt(4) ----
__global__ __launch_bounds__(512, 2) void conv_gemm(
    const unsigned short* __restrict__ WpF,
    const unsigned short* __restrict__ Xp,
    const float* __restrict__ bias,
    float* __restrict__ out)
{
  __shared__ __attribute__((aligned(16))) unsigned short lds[3][BUF_EL];  // 96 KB

  int bid = blockIdx.x;
  int wg = (bid & 7) * (GRID_MAIN/8) + (bid >> 3);   // XCD-bijective (1176%8==0)
  int cotile = wg % NT_CO;
  int stile  = wg / NT_CO;

  const int tid   = threadIdx.x;
  const int lane  = tid & 63;
  const int wv    = tid >> 6;       // 0..7
  const int wm    = wv >> 2;        // 0..1  (M / Cout position)
  const int wn    = wv & 3;         // 0..3  (N / spatial position)
  const int lanep = lane & 15;
  const int laneq = lane >> 4;
  const int l3    = lane >> 3;      // staging row within 8-row chunk
  const int l7    = lane & 7;       // staging 16B slot within 128B row
  const int gsl   = (l7 ^ l3) << 3; // pre-swizzled source chunk offset (elements)

  // A fragment pointers: aP[mf][ (2t+kk)*64 ] is this lane's 16B fragment
  const short8* aP[4];
  #pragma unroll
  for (int mf = 0; mf < 4; ++mf)
    aP[mf] = ((const short8*)WpF) + ((size_t)(cotile*8 + wm*4 + mf)*54)*64 + lane;

  // B staging: 32 chunks of 8 rows; wave wv handles chunks i*8+wv, i=0..3
  const unsigned short* bSrc[4];
  int bOff[4];
  #pragma unroll
  for (int i = 0; i < 4; ++i) {
    int cbk = i*8 + wv;
    int rb  = cbk*8 + l3;
    int f   = stile*BN + rb;
    int n   = f / SPAT, sp = f % SPAT;
    bSrc[i] = Xp + (((size_t)n*HP + sp/HW)*HP + sp%HW)*C_IN + gsl;
    bOff[i] = cbk*512;
  }

  // B ds_read fragment base (elements; nf adds nf*1024; kk flips XOR 32)
  const int bRd = (wn*64 + lanep)*64 + ((laneq ^ (lanep & 7)) << 3);

  f32x4 acc[4][4];
  #pragma unroll
  for (int mf = 0; mf < 4; ++mf)
    #pragma unroll
    for (int nf = 0; nf < 4; ++nf)
      acc[mf][nf] = (f32x4){0.f, 0.f, 0.f, 0.f};

  // K-tile t -> B image offset (all 64 K of a tile sit in one conv position)
  auto bOffOf = [](int t) {
    int pos = t / 3;                 // 0..8
    int c0  = (t - pos*3) * 64;      // 0,64,128
    int kh  = pos / 3, kw = pos - kh*3;
    return (kh*HP + kw)*C_IN + c0;
  };

  auto stage = [&](int t, unsigned short* base) {
    const int bo = bOffOf(t);
    #pragma unroll
    for (int i = 0; i < 4; ++i)
      async_load16(bSrc[i] + bo, base + bOff[i]);
  };

  short8 aA[8], aB[8];   // A fragment double buffer: [kk*4+mf]

  // One phase = one K=64 tile.
#define PHASE(LB, AC, AN, DO_PREF, T1, STAGE_STMT, VM_STMT, DO_BAR)         \
  {                                                                         \
    const unsigned short* lb_ = (LB);                                       \
    short8 bv0_[4], bv1_[4];                                                \
    _Pragma("unroll")                                                       \
    for (int nf = 0; nf < 4; ++nf) bv0_[nf] = *(const short8*)&lb_[bRd + nf*1024];        \
    _Pragma("unroll")                                                       \
    for (int nf = 0; nf < 4; ++nf) bv1_[nf] = *(const short8*)&lb_[(bRd + nf*1024) ^ 32]; \
    if (DO_PREF) {                                                          \
      _Pragma("unroll")                                                     \
      for (int kk = 0; kk < 2; ++kk)                                        \
        _Pragma("unroll")                                                   \
        for (int mf = 0; mf < 4; ++mf)                                      \
          AN[kk*4+mf] = aP[mf][(2*(T1)+kk)*64];                             \
    }                                                                       \
    SBAR0();                                                                \
    STAGE_STMT;                                                             \
    SBAR0();                                                                \
    __builtin_amdgcn_s_setprio(1);                                          \
    _Pragma("unroll")                                                       \
    for (int mf = 0; mf < 4; ++mf)                                          \
      _Pragma("unroll")                                                     \
      for (int nf = 0; nf < 4; ++nf)                                        \
        acc[mf][nf] = __builtin_amdgcn_mfma_f32_16x16x32_bf16(              \
            AC[mf], bv0_[nf], acc[mf][nf], 0, 0, 0);                        \
    _Pragma("unroll")                                                       \
    for (int mf = 0; mf < 4; ++mf)                                          \
      _Pragma("unroll")                                                     \
      for (int nf = 0; nf < 4; ++nf)                                        \
        acc[mf][nf] = __builtin_amdgcn_mfma_f32_16x16x32_bf16(              \
            AC[4+mf], bv1_[nf], acc[mf][nf], 0, 0, 0);                      \
    __builtin_amdgcn_s_setprio(0);                                          \
    SBAR0();                                                                \
    VM_STMT;                                                                \
    if (DO_BAR) {                                                           \
      __builtin_amdgcn_s_barrier();                                         \
      SBAR0();                                                              \
    }                                                                       \
  }

  unsigned short* b0 = &lds[0][0];
  unsigned short* b1 = &lds[1][0];
  unsigned short* b2 = &lds[2][0];

  // prologue: A(0) into aA; stage tiles 0,1; wait stage(0) landed
  #pragma unroll
  for (int kk = 0; kk < 2; ++kk)
    #pragma unroll
    for (int mf = 0; mf < 4; ++mf)
      aA[kk*4+mf] = aP[mf][kk*64];
  SBAR0();
  stage(0, b0);
  stage(1, b1);
  SBAR0();
  vm4();
  __builtin_amdgcn_s_barrier();
  SBAR0();

  // main loop: tiles 0..23, unrolled by 6 (slot period 3 x A-pingpong period 2)
  for (int t0 = 0; t0 < 24; t0 += 6) {
    PHASE(b0, aA, aB, true, t0+1, { stage(t0+2, b2); }, vm4(), true);
    PHASE(b1, aB, aA, true, t0+2, { stage(t0+3, b0); }, vm4(), true);
    PHASE(b2, aA, aB, true, t0+3, { stage(t0+4, b1); }, vm4(), true);
    PHASE(b0, aB, aA, true, t0+4, { stage(t0+5, b2); }, vm4(), true);
    PHASE(b1, aA, aB, true, t0+5, { stage(t0+6, b0); }, vm4(), true);
    PHASE(b2, aB, aA, true, t0+6, { stage(t0+7, b1); }, vm4(), true);
  }
  // t=24 (slot 0, AC=aA): stage last tile 26 -> slot 2
  PHASE(b0, aA, aB, true, 25, { stage(26, b2); }, vm4(), true);
  // t=25 (slot 1, AC=aB): prefetch A(26), drain staging fully
  PHASE(b1, aB, aA, true, 26, {}, vm0(), true);
  // t=26 (slot 2, AC=aA): last tile
  PHASE(b2, aA, aB, false, 0, {}, {}, false);
#undef PHASE

  // ---- epilogue: D col = lane&15 -> spatial, row = laneq*4+i -> Cout ----
  const int coB = cotile*BM + wm*64;
  const int fB  = stile*BN + wn*64;
  #pragma unroll
  for (int nf = 0; nf < 4; ++nf) {
    int f  = fB + nf*16 + lanep;
    int n  = f / SPAT;
    int sp = f % SPAT;
    float* obase = out + (size_t)n*C_OUT*SPAT + sp;
    #pragma unroll
    for (int mf = 0; mf < 4; ++mf) {
      #pragma unroll
      for (int i = 0; i < 4; ++i) {
        int co = coB + mf*16 + laneq*4 + i;
        obase[(size_t)co*SPAT] = acc[mf][nf][i] + bias[co];
      }
    }
  }
}

// ---- fallback: direct fp32 conv (used only if ws too small) ----
__global__ void conv_naive(const float* __restrict__ x, const float* __restrict__ W,
                           const float* __restrict__ bias, float* __restrict__ out) {
  size_t idx = (size_t)blockIdx.x*256 + threadIdx.x;
  if (idx >= (size_t)N_IMG*C_OUT*SPAT) return;
  int s  = idx % SPAT;
  int co = (int)((idx / SPAT) % C_OUT);
  int n  = (int)(idx / ((size_t)SPAT*C_OUT));
  int h = s / HW, w = s % HW;
  float acc = bias[co];
  for (int c = 0; c < C_IN; ++c)
    for (int kh = 0; kh < 3; ++kh) {
      int hh = h + kh - 1;
      if (hh < 0 || hh >= HW) continue;
      for (int kw = 0; kw < 3; ++kw) {
        int ww = w + kw - 1;
        if (ww < 0 || ww >= HW) continue;
        acc += x[(((size_t)n*C_IN + c)*HW + hh)*HW + ww]
             * W[(((size_t)co*C_IN + c)*3 + kh)*3 + kw];
      }
    }
  out[idx] = acc;
}

extern "C" void kernel_launch(void* const* d_in, const int* in_sizes, int n_in,
                              void* d_out, int out_size, void* d_ws, size_t ws_size,
                              hipStream_t stream) {
  const float* x = (const float*)d_in[0];
  const float* W = (const float*)d_in[1];
  const float* b = (const float*)d_in[2];
  float* out = (float*)d_out;

  const size_t WP_ELEMS = (size_t)C_OUT*KTOT;             // 663,552
  const size_t XP_ELEMS = (size_t)N_IMG*HP*HP*C_IN;       // 20,668,416
  const size_t NEED = (WP_ELEMS + XP_ELEMS)*2;            // ~40.7 MB

  if (ws_size >= NEED) {
    unsigned short* WpF = (unsigned short*)d_ws;
    unsigned short* Xp  = WpF + WP_ELEMS;                 // 16B-aligned
    zero_border<<<(N_IMG*228*C_IN + 255)/256, 256, 0, stream>>>(Xp);
    pack_w<<<(int)((WP_ELEMS + 255)/256), 256, 0, stream>>>(W, WpF);
    pack_x<<<N_IMG*HW*3, 256, 0, stream>>>(x, Xp);
    conv_gemm<<<GRID_MAIN, 512, 0, stream>>>(WpF, Xp, b, out);
  } else {
    size_t total = (size_t)N_IMG*C_OUT*SPAT;
    conv_naive<<<(int)((total + 255)/256), 256, 0, stream>>>(x, W, b, out);
  }
}

// Round 6
// 172.191 us; speedup vs baseline: 1.1887x; 1.1887x over previous
//
#include <hip/hip_runtime.h>
#include <cstdint>
#include <cstddef>

#define N_IMG 32
#define C_IN 192
#define HW 56
#define SPAT 3136
#define C_OUT 384
#define HP 58
#define KPOS 9
#define KTOT 1728          // 9*192
#define NPH 54             // K-phases of 32

#define BM 128             // Cout per block
#define BN 256             // spatial-flat per block
#define NT_CO 3
#define NT_S  392          // 100352/256 exact
#define GRID_MAIN (NT_CO*NT_S)   // 1176, %8 == 0

#define BUF_EL 12288       // (128+256)*32 bf16 elements per buffer (24KB)
#define B_BASE 4096        // B region starts after A[128][32]

typedef __attribute__((ext_vector_type(8))) short short8;
typedef __attribute__((ext_vector_type(4))) float f32x4;

__device__ __forceinline__ unsigned short f2bf(float f) {
  union { float f; unsigned u; } v; v.f = f;
  unsigned u = v.u;
  unsigned r = (u + 0x7FFFu + ((u >> 16) & 1u)) >> 16;
  return (unsigned short)r;
}

__device__ __forceinline__ void async_load16(const void* gsrc, void* ldst) {
  __builtin_amdgcn_global_load_lds(
      (const __attribute__((address_space(1))) unsigned int*)gsrc,
      (__attribute__((address_space(3))) unsigned int*)ldst,
      16, 0, 0);
}

__device__ __forceinline__ void vm3() { asm volatile("s_waitcnt vmcnt(3)" ::: "memory"); }
__device__ __forceinline__ void vm0() { asm volatile("s_waitcnt vmcnt(0)" ::: "memory"); }
#define SBAR0() __builtin_amdgcn_sched_barrier(0)

// ---- prep: W (Cout,C,3,3) f32 -> Wp[co][pos][c] bf16 (K linear = pos*192+c) ----
__global__ void pack_w(const float* __restrict__ W, unsigned short* __restrict__ Wp) {
  int idx = blockIdx.x*256 + threadIdx.x;
  if (idx >= C_OUT*KPOS*C_IN) return;
  int c   = idx % C_IN;
  int pos = (idx / C_IN) % KPOS;
  int co  = idx / (C_IN*KPOS);
  float v = W[((size_t)co*C_IN + c)*KPOS + pos];
  Wp[idx] = f2bf(v);
}

// ---- prep: zero pad border of Xp[n][58][58][192] ----
__global__ void zero_border(unsigned short* __restrict__ Xp) {
  int idx = blockIdx.x*256 + threadIdx.x;
  if (idx >= N_IMG*228*C_IN) return;
  int c    = idx % C_IN;
  int cell = (idx / C_IN) % 228;
  int n    = idx / (C_IN*228);
  int hh, ww;
  if (cell < 116) { hh = (cell < 58) ? 0 : 57; ww = cell % 58; }
  else { int b2 = cell - 116; ww = (b2 < 56) ? 0 : 57; hh = 1 + (b2 % 56); }
  Xp[(((size_t)n*HP + hh)*HP + ww)*C_IN + c] = 0;
}

// ---- prep: x NCHW f32 -> Xp padded NHWC bf16 (interior) ----
__global__ void pack_x(const float* __restrict__ x, unsigned short* __restrict__ Xp) {
  __shared__ float tile[64*57];
  int b  = blockIdx.x;
  int cb = b % 3;
  int h  = (b/3) % HW;
  int n  = b / (3*HW);
  int tid = threadIdx.x;
  const float* src = x + (size_t)n*C_IN*SPAT + (size_t)cb*64*SPAT + h*HW;
  #pragma unroll
  for (int i = 0; i < 14; ++i) {
    int idx = i*256 + tid;
    int c = idx / HW, w = idx % HW;
    tile[c*57 + w] = src[(size_t)c*SPAT + w];
  }
  __syncthreads();
  unsigned short* dst = Xp + (((size_t)n*HP + h + 1)*HP + 1)*C_IN + cb*64;
  #pragma unroll
  for (int i = 0; i < 14; ++i) {
    int idx = i*256 + tid;
    int w = idx / 64, c = idx % 64;
    dst[(size_t)w*C_IN + c] = f2bf(tile[c*57 + w]);
  }
}

// ---- main: implicit-GEMM conv, 128x256 tile, 8 waves, ring-3 K=32 (24KB bufs),
//      2 blocks/CU, one barrier per phase, counted vmcnt(3) ----
__global__ __launch_bounds__(512, 4) void conv_gemm(
    const unsigned short* __restrict__ Wp,
    const unsigned short* __restrict__ Xp,
    const float* __restrict__ bias,
    float* __restrict__ out)
{
  __shared__ __attribute__((aligned(16))) unsigned short lds[3][BUF_EL];  // 72 KB

  int bid = blockIdx.x;
  int wg = (bid & 7) * (GRID_MAIN/8) + (bid >> 3);   // XCD-bijective (1176%8==0)
  int cotile = wg % NT_CO;
  int stile  = wg / NT_CO;

  const int tid   = threadIdx.x;
  const int lane  = tid & 63;
  const int wv    = tid >> 6;       // 0..7
  const int wm    = wv >> 2;        // 0..1  (M / Cout position)
  const int wn    = wv & 3;         // 0..3  (N / spatial position)
  const int lanep = lane & 15;
  const int laneq = lane >> 4;
  const int r4    = (lane >> 2) & 15;  // staging row within 16-row chunk
  const int c4    = lane & 3;          // staging 16B slot within 64B row
  // write-side swizzle: slot c4 holds global chunk c4 ^ ((row>>1)&3), row%16==r4
  const int gsl   = (c4 ^ ((r4 >> 1) & 3)) << 3;   // source chunk offset (elements)

  // ---- staging source pointers ----
  // A: 8 chunks of 16 rows; wave wv stages chunk wv (rows wv*16+r4)
  const unsigned short* aSrc = Wp + (size_t)(cotile*BM + wv*16 + r4)*KTOT + gsl;
  // B: 16 chunks of 16 rows; wave wv stages chunks wv*2, wv*2+1
  const unsigned short* bSrc0;
  const unsigned short* bSrc1;
  {
    int f0 = stile*BN + (wv*2 + 0)*16 + r4;
    int n0 = f0 / SPAT, sp0 = f0 % SPAT;
    bSrc0 = Xp + (((size_t)n0*HP + sp0/HW)*HP + sp0%HW)*C_IN + gsl;
    int f1 = stile*BN + (wv*2 + 1)*16 + r4;
    int n1 = f1 / SPAT, sp1 = f1 % SPAT;
    bSrc1 = Xp + (((size_t)n1*HP + sp1/HW)*HP + sp1%HW)*C_IN + gsl;
  }

  // ds_read fragment bases (elements); frag mf/nf adds mf*512
  const int rsw = (laneq ^ ((lanep >> 1) & 3)) << 3;   // read-side slot swizzle
  const int aRd = (wm*64 + lanep)*32 + rsw;
  const int bRd = B_BASE + (wn*64 + lanep)*32 + rsw;

  f32x4 acc[4][4];
  #pragma unroll
  for (int mf = 0; mf < 4; ++mf)
    #pragma unroll
    for (int nf = 0; nf < 4; ++nf)
      acc[mf][nf] = (f32x4){0.f, 0.f, 0.f, 0.f};

  // phase t (K=32) -> A k-offset t*32; B image offset: pos = t/6, c0 = (t%6)*32
  auto stage = [&](int t, unsigned short* base) {
    int pos = t / 6;
    int c0  = (t - pos*6) * 32;
    int kh  = pos / 3, kw = pos - kh*3;
    int bo  = (kh*HP + kw)*C_IN + c0;
    async_load16(aSrc + t*32, base + wv*512);
    async_load16(bSrc0 + bo, base + B_BASE + (wv*2 + 0)*512);
    async_load16(bSrc1 + bo, base + B_BASE + (wv*2 + 1)*512);
  };

  // One phase = one K=32 tile: 8 ds_read_b128, 3 staging loads, 16 MFMA, vm, bar.
#define PHASE(LB, STAGE_STMT, VM_STMT, DO_BAR)                              \
  {                                                                         \
    const unsigned short* lb_ = (LB);                                       \
    short8 av_[4], bv_[4];                                                  \
    _Pragma("unroll")                                                       \
    for (int mf = 0; mf < 4; ++mf) av_[mf] = *(const short8*)&lb_[aRd + mf*512]; \
    _Pragma("unroll")                                                       \
    for (int nf = 0; nf < 4; ++nf) bv_[nf] = *(const short8*)&lb_[bRd + nf*512]; \
    STAGE_STMT;                                                             \
    __builtin_amdgcn_s_setprio(1);                                          \
    _Pragma("unroll")                                                       \
    for (int mf = 0; mf < 4; ++mf)                                          \
      _Pragma("unroll")                                                     \
      for (int nf = 0; nf < 4; ++nf)                                        \
        acc[mf][nf] = __builtin_amdgcn_mfma_f32_16x16x32_bf16(              \
            av_[mf], bv_[nf], acc[mf][nf], 0, 0, 0);                        \
    __builtin_amdgcn_s_setprio(0);                                          \
    VM_STMT;                                                                \
    if (DO_BAR) {                                                           \
      __builtin_amdgcn_s_barrier();                                         \
      SBAR0();                                                              \
    }                                                                       \
  }

  unsigned short* b0 = &lds[0][0];
  unsigned short* b1 = &lds[1][0];
  unsigned short* b2 = &lds[2][0];

  // prologue: stage phases 0,1 (6 loads/wave); wait stage(0) landed
  stage(0, b0);
  stage(1, b1);
  vm3();
  __builtin_amdgcn_s_barrier();
  SBAR0();

  // main loop: phases 0..50 (slots cycle 0,1,2), 2-deep counted vmcnt(3)
  for (int t0 = 0; t0 < 51; t0 += 3) {
    PHASE(b0, (stage(t0 + 2, b2)), vm3(), true);
    PHASE(b1, (stage(t0 + 3, b0)), vm3(), true);
    PHASE(b2, (stage(t0 + 4, b1)), vm3(), true);
  }
  // t=51 (slot 0): stage last phase 53 -> slot 2
  PHASE(b0, (stage(53, b2)), vm3(), true);
  // t=52 (slot 1): drain fully so phase 53's buffer is visible
  PHASE(b1, (void)0, vm0(), true);
  // t=53 (slot 2): last phase, no wait/barrier
  PHASE(b2, (void)0, (void)0, false);
#undef PHASE

  // ---- epilogue: D col = lane&15 -> spatial, row = laneq*4+i -> Cout ----
  const int coB = cotile*BM + wm*64;
  const int fB  = stile*BN + wn*64;
  #pragma unroll
  for (int nf = 0; nf < 4; ++nf) {
    int f  = fB + nf*16 + lanep;
    int n  = f / SPAT;
    int sp = f % SPAT;
    float* obase = out + (size_t)n*C_OUT*SPAT + sp;
    #pragma unroll
    for (int mf = 0; mf < 4; ++mf) {
      #pragma unroll
      for (int i = 0; i < 4; ++i) {
        int co = coB + mf*16 + laneq*4 + i;
        obase[(size_t)co*SPAT] = acc[mf][nf][i] + bias[co];
      }
    }
  }
}

// ---- fallback: direct fp32 conv (used only if ws too small) ----
__global__ void conv_naive(const float* __restrict__ x, const float* __restrict__ W,
                           const float* __restrict__ bias, float* __restrict__ out) {
  size_t idx = (size_t)blockIdx.x*256 + threadIdx.x;
  if (idx >= (size_t)N_IMG*C_OUT*SPAT) return;
  int s  = idx % SPAT;
  int co = (int)((idx / SPAT) % C_OUT);
  int n  = (int)(idx / ((size_t)SPAT*C_OUT));
  int h = s / HW, w = s % HW;
  float acc = bias[co];
  for (int c = 0; c < C_IN; ++c)
    for (int kh = 0; kh < 3; ++kh) {
      int hh = h + kh - 1;
      if (hh < 0 || hh >= HW) continue;
      for (int kw = 0; kw < 3; ++kw) {
        int ww = w + kw - 1;
        if (ww < 0 || ww >= HW) continue;
        acc += x[(((size_t)n*C_IN + c)*HW + hh)*HW + ww]
             * W[(((size_t)co*C_IN + c)*3 + kh)*3 + kw];
      }
    }
  out[idx] = acc;
}

extern "C" void kernel_launch(void* const* d_in, const int* in_sizes, int n_in,
                              void* d_out, int out_size, void* d_ws, size_t ws_size,
                              hipStream_t stream) {
  const float* x = (const float*)d_in[0];
  const float* W = (const float*)d_in[1];
  const float* b = (const float*)d_in[2];
  float* out = (float*)d_out;

  const size_t WP_ELEMS = (size_t)C_OUT*KTOT;             // 663,552
  const size_t XP_ELEMS = (size_t)N_IMG*HP*HP*C_IN;       // 20,668,416
  const size_t NEED = (WP_ELEMS + XP_ELEMS)*2;            // ~40.7 MB

  if (ws_size >= NEED) {
    unsigned short* Wp = (unsigned short*)d_ws;
    unsigned short* Xp = Wp + WP_ELEMS;                   // 16B-aligned
    zero_border<<<(N_IMG*228*C_IN + 255)/256, 256, 0, stream>>>(Xp);
    pack_w<<<(int)((WP_ELEMS + 255)/256), 256, 0, stream>>>(W, Wp);
    pack_x<<<N_IMG*HW*3, 256, 0, stream>>>(x, Xp);
    conv_gemm<<<GRID_MAIN, 512, 0, stream>>>(Wp, Xp, b, out);
  } else {
    size_t total = (size_t)N_IMG*C_OUT*SPAT;
    conv_naive<<<(int)((total + 255)/256), 256, 0, stream>>>(x, W, b, out);
  }
}